// Round 11
// baseline (211.348 us; speedup 1.0000x reference)
//
#include <hip/hip_runtime.h>
#include <hip/hip_bf16.h>

typedef __bf16 bf16;
typedef __bf16 bf16x4 __attribute__((ext_vector_type(4)));
typedef __bf16 bf16x8 __attribute__((ext_vector_type(8)));
typedef float  f32x4  __attribute__((ext_vector_type(4)));
typedef float  f32x16 __attribute__((ext_vector_type(16)));
typedef unsigned int u32;

#define B_   2
#define SQ_  2048
#define SK_  2048
#define H_   2048
#define NH_  16
#define HD_  128
#define BH_  (B_*NH_)

// async 16B global->LDS; LDS dest must be wave-uniform base (+lane*16 by HW)
__device__ inline void gl_lds16(const bf16* g, bf16* l) {
  __builtin_amdgcn_global_load_lds(
      (const __attribute__((address_space(1))) u32*)(const void*)g,
      (__attribute__((address_space(3))) u32*)(void*)l,
      16, 0, 0);
}

__device__ inline float exp2_fast(float x) {
  float r; asm("v_exp_f32 %0, %1" : "=v"(r) : "v"(x)); return r;
}

union PW { u32 w[4]; bf16x8 v; };

// ------------- fused fp32 -> bf16 convert for hidden / w_q / w_proj --------
__global__ __launch_bounds__(256) void cvt3_f32_bf16(const float* __restrict__ a, bf16* __restrict__ ao,
                                                     const float* __restrict__ b, bf16* __restrict__ bo,
                                                     const float* __restrict__ c, bf16* __restrict__ co) {
  const int blk = blockIdx.x;
  const float* in; bf16* out; int n4, bstart, nblk;
  if (blk < 1024)      { in = a; out = ao; n4 = (B_ * SQ_ * H_) / 4; bstart = 0;    nblk = 1024; }
  else if (blk < 1536) { in = b; out = bo; n4 = (H_ * H_) / 4;       bstart = 1024; nblk = 512; }
  else                 { in = c; out = co; n4 = (H_ * H_) / 4;       bstart = 1536; nblk = 512; }
  int i = (blk - bstart) * 256 + threadIdx.x;
  const int stride = nblk * 256;
  for (; i < n4; i += stride) {
    float4 v = ((const float4*)in)[i];
    bf16x4 w; w[0] = (bf16)v.x; w[1] = (bf16)v.y; w[2] = (bf16)v.z; w[3] = (bf16)v.w;
    ((bf16x4*)out)[i] = w;
  }
}

// ---- fused transpose+convert: key [bh][128][2048] -> [bh][2048][128] bf16
//                               value [bh][2048][128] -> [bh][128][2048] bf16
__global__ __launch_bounds__(256) void transpose_cvt2(const float* __restrict__ key,
                                                      const float* __restrict__ value,
                                                      bf16* __restrict__ kout,
                                                      bf16* __restrict__ vout) {
  __shared__ float tile[64][65];
  const int id = blockIdx.x;
  const float* src; bf16* dst; int R, C, r0, c0, bh;
  if (id < 2048) {            // key slices: R=HD, C=SK
    src = key; dst = kout; R = HD_; C = SK_;
    c0 = (id & 31) * 64; r0 = ((id >> 5) & 1) * 64; bh = id >> 6;
  } else {                    // value slices: R=SK, C=HD
    const int j = id - 2048;
    src = value; dst = vout; R = SK_; C = HD_;
    c0 = (j & 1) * 64; r0 = ((j >> 1) & 31) * 64; bh = j >> 6;
  }
  src += (size_t)bh * R * C;
  dst += (size_t)bh * R * C;
  const int t = threadIdx.x;
  const int tx = t & 15, ty = t >> 4;
#pragma unroll
  for (int p = 0; p < 4; ++p) {
    int rr = ty + p * 16;
    float4 v = *(const float4*)&src[(size_t)(r0 + rr) * C + c0 + tx * 4];
    tile[rr][tx * 4 + 0] = v.x; tile[rr][tx * 4 + 1] = v.y;
    tile[rr][tx * 4 + 2] = v.z; tile[rr][tx * 4 + 3] = v.w;
  }
  __syncthreads();
#pragma unroll
  for (int p = 0; p < 4; ++p) {
    int cc = ty + p * 16;
    bf16x4 w;
#pragma unroll
    for (int i = 0; i < 4; ++i) w[i] = (bf16)tile[tx * 4 + i][cc];
    *(bf16x4*)&dst[(size_t)(c0 + cc) * R + r0 + tx * 4] = w;
  }
}

// ---------------- 128x128-tile bf16 GEMM, C = (A @ Bw^T + bias) * osc -------
template <typename OutT>
__global__ __launch_bounds__(256) void gemm_bt(const bf16* __restrict__ A,
                                               const bf16* __restrict__ Bw,
                                               const float* __restrict__ bias,
                                               OutT* __restrict__ C,
                                               int M, int N, int K, float osc) {
  __shared__ bf16 Abuf[128 * 32];
  __shared__ bf16 Bbuf[128 * 32];
  const int nbn = N >> 7;
  int wg = blockIdx.x, nwg = gridDim.x;
  int swz = (nwg & 7) ? wg : ((wg & 7) * (nwg >> 3) + (wg >> 3));  // XCD swizzle
  int bm = swz / nbn, bn = swz % nbn;
  const int t = threadIdx.x, lane = t & 63, wid = t >> 6;
  const int r = lane & 15, g = lane >> 4;
  const int wr = wid >> 1, wc = wid & 1;
  const size_t m0 = (size_t)bm * 128, n0 = (size_t)bn * 128;

  f32x4 acc[4][4];
#pragma unroll
  for (int m = 0; m < 4; ++m)
#pragma unroll
    for (int n = 0; n < 4; ++n) acc[m][n] = (f32x4){0.f, 0.f, 0.f, 0.f};

  for (int k0 = 0; k0 < K; k0 += 32) {
    __syncthreads();
#pragma unroll
    for (int p = 0; p < 2; ++p) {
      int c = p * 256 + t;
      int row = c >> 2, off = c & 3;  // 128 rows x 4 16B-chunks
      gl_lds16(A + (m0 + row) * K + k0 + off * 8, &Abuf[(p * 256 + wid * 64) * 8]);
      gl_lds16(Bw + (n0 + row) * K + k0 + off * 8, &Bbuf[(p * 256 + wid * 64) * 8]);
    }
    __syncthreads();
    bf16x8 af[4], bfr[4];
#pragma unroll
    for (int m = 0; m < 4; ++m)
      af[m] = *(const bf16x8*)&Abuf[(wr * 64 + m * 16 + r) * 32 + g * 8];
#pragma unroll
    for (int n = 0; n < 4; ++n)
      bfr[n] = *(const bf16x8*)&Bbuf[(wc * 64 + n * 16 + r) * 32 + g * 8];
#pragma unroll
    for (int m = 0; m < 4; ++m)
#pragma unroll
      for (int n = 0; n < 4; ++n)
        acc[m][n] = __builtin_amdgcn_mfma_f32_16x16x32_bf16(af[m], bfr[n], acc[m][n], 0, 0, 0);
  }

  float bv[4];
#pragma unroll
  for (int n = 0; n < 4; ++n) bv[n] = bias[n0 + wc * 64 + n * 16 + r];
#pragma unroll
  for (int m = 0; m < 4; ++m)
#pragma unroll
    for (int n = 0; n < 4; ++n)
#pragma unroll
      for (int rr = 0; rr < 4; ++rr) {
        size_t row = m0 + wr * 64 + m * 16 + g * 4 + rr;
        size_t col = n0 + wc * 64 + n * 16 + r;
        C[row * N + col] = (OutT)((acc[m][n][rr] + bv[n]) * osc);
      }
}

// -------- causal flash attention: swapped-operand 32x32, split-kv, T15 ------
// Q pre-scaled by (1/sqrt(128))*log2(e).
// Block = 4 waves x 32 q-rows. Swapped QK^T: S^T = mfma(K, Q), lane owns one
// q-row. Per-iter pipeline (T15 dep-break): QK(st) -> PV(st-1) -> SM(st);
// PV(prev) is independent of QK/SM so the scheduler overlaps MFMA with VALU.
// K double-buffered; V TRIPLE-buffered (PV reads V[vp] while staging hits
// V[vn]; vp/vc/vn always distinct). LDS 80KB/block -> 2 blocks/CU.
// K LDS: [64 s][16 chunks] XOR ^(s&15); V LDS: [64 sr][16 chunks] XOR ^(sr&15).
__global__ __launch_bounds__(256, 2) void flash_attn(const bf16* __restrict__ Q,
                                                     const bf16* __restrict__ Kt,
                                                     const bf16* __restrict__ Vt,
                                                     bf16* __restrict__ O,
                                                     bf16* __restrict__ part,
                                                     float2* __restrict__ mlbuf) {
  __shared__ bf16 Klds[2][64 * 128];
  __shared__ bf16 Vlds[3][64 * 128];

  const int id = blockIdx.x;
  const int pr = (id >> 3) & 7;
  const int hf = (id >> 6) & 1;
  const int bh = (id & 7) + 8 * (id >> 7);
  const int qtA = 15 - pr, qtB = pr;
  const int nA = 2 * qtA + 2, nB = 2 * qtB + 2;
  const int b = bh >> 4, h = bh & 15;
  const int t = threadIdx.x, lane = t & 63, wid = t >> 6;
  const int l5 = lane & 31, hiL = lane >> 5;

  const bf16* Kbase = Kt + (size_t)bh * SK_ * HD_;
  const bf16* Vbase = Vt + (size_t)bh * HD_ * SK_;

  // staging source offsets (linear LDS dest + inverse-swizzled global source)
  u32 kSrc[4], vSrc[4];
#pragma unroll
  for (int p = 0; p < 4; ++p) {
    int c = p * 256 + t;
    { int row = c >> 4, off = c & 15, src = off ^ (row & 15);
      kSrc[p] = (u32)(row * HD_ + src * 8); }
    { int srow = c >> 4, j = c & 15, gj = j ^ (srow & 15);
      int d = srow * 2 + (gj >> 3);
      vSrc[p] = (u32)(d * SK_ + (gj & 7) * 8); }
  }

  const int npass = hf ? 2 : 1;
#pragma unroll 1
  for (int ps = 0; ps < npass; ++ps) {
    int qt, lo, hi, partial;
    if (!hf)          { qt = qtA; lo = 0;  hi = 17; partial = 1; }
    else if (ps == 0) { qt = qtA; lo = 17; hi = nA; partial = 1; }
    else              { qt = qtB; lo = 0;  hi = nB; partial = 0; }
    const int qbw = qt * 128 + wid * 32;     // wave's q-row base
    const int q_lane = qbw + l5;             // this lane's q-row

    // Q B-fragments
    bf16x8 qf[8];
    {
      const size_t qrow = (size_t)(b * SQ_ + q_lane) * H_ + (size_t)h * HD_;
#pragma unroll
      for (int dt = 0; dt < 8; ++dt)
        qf[dt] = *(const bf16x8*)&Q[qrow + dt * 16 + 8 * hiL];
    }

    f32x16 acc[4];
#pragma unroll
    for (int n = 0; n < 4; ++n)
#pragma unroll
      for (int e = 0; e < 16; ++e) acc[n][e] = 0.f;
    float mrun = -3.0e38f, lpart = 0.f;

    // pipeline state
    bf16x8 paP[4];
    bool have_prev = false;
    int kc = 0, vp = 2, vc = 0, vn = 1;

    // prologue: protect V slots still being read by other waves' flush, then
    // stage kv tile lo
    __syncthreads();
    {
      const size_t ks = (size_t)lo * (64 * HD_), vs = (size_t)lo * 64;
#pragma unroll
      for (int p = 0; p < 4; ++p) {
        gl_lds16(Kbase + ks + kSrc[p], &Klds[0][(p * 256 + wid * 64) * 8]);
        gl_lds16(Vbase + vs + vSrc[p], &Vlds[0][(p * 256 + wid * 64) * 8]);
      }
    }
    asm volatile("s_waitcnt vmcnt(0)" ::: "memory");
    __syncthreads();

#pragma unroll 1
    for (int st = lo; st < hi; ++st) {
      if (st + 1 < hi) {
        const size_t ks = (size_t)(st + 1) * (64 * HD_), vs = (size_t)(st + 1) * 64;
#pragma unroll
        for (int p = 0; p < 4; ++p) {
          gl_lds16(Kbase + ks + kSrc[p], &Klds[kc ^ 1][(p * 256 + wid * 64) * 8]);
          gl_lds16(Vbase + vs + vSrc[p], &Vlds[vn][(p * 256 + wid * 64) * 8]);
        }
      }
      const int s0 = st * 64;
      const bool act = (s0 <= qbw + 31);   // wave-uniform

      f32x16 sv0, sv1;
      if (act) {
        // ---- S^T = K Q^T
#pragma unroll
        for (int e = 0; e < 16; ++e) { sv0[e] = 0.f; sv1[e] = 0.f; }
        __builtin_amdgcn_s_setprio(1);
#pragma unroll
        for (int dt = 0; dt < 8; ++dt) {
          const int dch = ((2 * dt + hiL) ^ (l5 & 15)) * 8;
          bf16x8 kf0 = *(const bf16x8*)&Klds[kc][l5 * 128 + dch];
          bf16x8 kf1 = *(const bf16x8*)&Klds[kc][(32 + l5) * 128 + dch];
          sv0 = __builtin_amdgcn_mfma_f32_32x32x16_bf16(kf0, qf[dt], sv0, 0, 0, 0);
          sv1 = __builtin_amdgcn_mfma_f32_32x32x16_bf16(kf1, qf[dt], sv1, 0, 0, 0);
        }
        __builtin_amdgcn_s_setprio(0);
      }

      // ---- PV(prev): independent of QK/SM above -> schedulable overlap
      if (have_prev) {
        const bf16* vbuf = &Vlds[vp][0];
        __builtin_amdgcn_s_setprio(1);
#pragma unroll
        for (int n = 0; n < 4; ++n) {
          const int sr = n * 16 + (l5 >> 1);
#pragma unroll
          for (int kt = 0; kt < 4; ++kt) {
            const int jj = ((((l5 & 1) << 3) | (2 * kt + hiL)) ^ (l5 >> 1));
            bf16x8 vf = *(const bf16x8*)&vbuf[sr * 128 + jj * 8];
            acc[n] = __builtin_amdgcn_mfma_f32_32x32x16_bf16(paP[kt], vf, acc[n], 0, 0, 0);
          }
        }
        __builtin_amdgcn_s_setprio(0);
        have_prev = false;
      }

      if (act) {
        // ---- causal mask (diagonal tiles only)
        if (s0 + 63 > qbw) {
#pragma unroll
          for (int r2 = 0; r2 < 16; ++r2) {
            const int kl = (r2 & 3) + 8 * (r2 >> 2) + 4 * hiL;
            if (s0 + kl > q_lane)      sv0[r2] = -3.0e38f;
            if (s0 + 32 + kl > q_lane) sv1[r2] = -3.0e38f;
          }
        }

        // ---- row stats + optional rescale (applied AFTER PV(prev) above)
        float pm = -3.0e38f;
#pragma unroll
        for (int r2 = 0; r2 < 16; ++r2) pm = fmaxf(pm, fmaxf(sv0[r2], sv1[r2]));
        pm = fmaxf(pm, __shfl_xor(pm, 32));
        if (!__all(pm <= mrun + 10.0f ? 1 : 0)) {
          const float mnew = fmaxf(mrun, pm);
          const float corr = exp2_fast(mrun - mnew);
          mrun = mnew; lpart *= corr;
          const int cb = __float_as_int(corr);
#pragma unroll
          for (int r2 = 0; r2 < 16; ++r2) {
            const int q2 = (r2 & 3) + 8 * (r2 >> 2) + 4 * hiL;
            const float cc = __int_as_float(__builtin_amdgcn_ds_bpermute(q2 * 4, cb));
#pragma unroll
            for (int n = 0; n < 4; ++n) acc[n][r2] *= cc;
          }
        }

        // ---- P = exp2(S - m) + partial l
        float psum = 0.f;
#pragma unroll
        for (int r2 = 0; r2 < 16; ++r2) {
          sv0[r2] = exp2_fast(sv0[r2] - mrun); psum += sv0[r2];
          sv1[r2] = exp2_fast(sv1[r2] - mrun); psum += sv1[r2];
        }
        lpart += psum;

        // ---- repack P -> PV A-frags (held for NEXT iter)
#pragma unroll
        for (int h2 = 0; h2 < 2; ++h2) {
          u32 pk[8], px[8];
#pragma unroll
          for (int j = 0; j < 8; ++j) {
            union { bf16 hh[2]; u32 u; } tt;
            float plo = h2 ? sv1[2 * j] : sv0[2 * j];
            float phi = h2 ? sv1[2 * j + 1] : sv0[2 * j + 1];
            tt.hh[0] = (bf16)plo; tt.hh[1] = (bf16)phi;
            pk[j] = tt.u;
          }
#pragma unroll
          for (int j = 0; j < 8; ++j) px[j] = (u32)__shfl_xor((int)pk[j], 32);
          PW a0, a1;
          a0.w[0] = hiL ? px[2] : pk[0]; a0.w[1] = hiL ? px[3] : pk[1];
          a0.w[2] = hiL ? pk[2] : px[0]; a0.w[3] = hiL ? pk[3] : px[1];
          a1.w[0] = hiL ? px[6] : pk[4]; a1.w[1] = hiL ? px[7] : pk[5];
          a1.w[2] = hiL ? pk[6] : px[4]; a1.w[3] = hiL ? pk[7] : px[5];
          paP[2 * h2]     = a0.v;
          paP[2 * h2 + 1] = a1.v;
        }
        have_prev = true;
      }

      asm volatile("s_waitcnt vmcnt(0)" ::: "memory");
      __syncthreads();
      kc ^= 1;
      const int ovp = vp; vp = vc; vc = vn; vn = ovp;
    }

    // ---- pipeline flush: PV of the last active tile (V slot vp intact;
    // next-pass staging is fenced by the prologue barrier)
    if (have_prev) {
      const bf16* vbuf = &Vlds[vp][0];
#pragma unroll
      for (int n = 0; n < 4; ++n) {
        const int sr = n * 16 + (l5 >> 1);
#pragma unroll
        for (int kt = 0; kt < 4; ++kt) {
          const int jj = ((((l5 & 1) << 3) | (2 * kt + hiL)) ^ (l5 >> 1));
          bf16x8 vf = *(const bf16x8*)&vbuf[sr * 128 + jj * 8];
          acc[n] = __builtin_amdgcn_mfma_f32_32x32x16_bf16(paP[kt], vf, acc[n], 0, 0, 0);
        }
      }
      have_prev = false;
    }

    // ---- epilogue
    float ltot = lpart + __shfl_xor(lpart, 32);
    if (partial) {
      const int slot = (hf * 8 + pr) * 32 + bh;
      bf16* pbase = part + (size_t)slot * (128 * 128);
#pragma unroll
      for (int n = 0; n < 4; ++n)
#pragma unroll
        for (int r2 = 0; r2 < 16; ++r2) {
          const int rowt = wid * 32 + (r2 & 3) + 8 * (r2 >> 2) + 4 * hiL;
          pbase[rowt * 128 + n * 32 + l5] = (bf16)acc[n][r2];
        }
      if (lane < 32)
        mlbuf[(size_t)slot * 128 + wid * 32 + lane] = float2{mrun, ltot};
    } else {
      const float inv = 1.0f / ltot;
      const int ib = __float_as_int(inv);
#pragma unroll
      for (int r2 = 0; r2 < 16; ++r2) {
        const int q2 = (r2 & 3) + 8 * (r2 >> 2) + 4 * hiL;
        const float ic = __int_as_float(__builtin_amdgcn_ds_bpermute(q2 * 4, ib));
        const size_t rowg = (size_t)(b * SQ_ + qbw + q2);
#pragma unroll
        for (int n = 0; n < 4; ++n)
          O[rowg * H_ + (size_t)h * HD_ + n * 32 + l5] = (bf16)(acc[n][r2] * ic);
      }
    }
  }
}

// -------- merge the two kv-halves of each qtA tile (vectorized bf16x8) ------
__global__ __launch_bounds__(256) void flash_merge(const bf16* __restrict__ part,
                                                   const float2* __restrict__ mlbuf,
                                                   bf16* __restrict__ O) {
  const int gid = blockIdx.x * 256 + threadIdx.x;   // 524288 threads
  const int idx = gid >> 4;                         // row index in [0, 32768)
  const int d8 = (gid & 15) * 8;
  const int row = idx & 127;
  const int bh = (idx >> 7) & 31;
  const int pr = idx >> 12;
  const int qtA = 15 - pr;
  const int b = bh >> 4, h = bh & 15;
  const int slot0 = pr * 32 + bh;
  const int slot1 = (8 + pr) * 32 + bh;
  const float2 ml0 = mlbuf[(size_t)slot0 * 128 + row];
  const float2 ml1 = mlbuf[(size_t)slot1 * 128 + row];
  const float M = fmaxf(ml0.x, ml1.x);
  const float c0 = exp2_fast(ml0.x - M);
  const float c1 = exp2_fast(ml1.x - M);
  const float inv = 1.0f / (c0 * ml0.y + c1 * ml1.y);
  const bf16x8 a0 = *(const bf16x8*)&part[(size_t)slot0 * (128 * 128) + row * 128 + d8];
  const bf16x8 a1 = *(const bf16x8*)&part[(size_t)slot1 * (128 * 128) + row * 128 + d8];
  bf16x8 o;
#pragma unroll
  for (int j = 0; j < 8; ++j)
    o[j] = (bf16)((c0 * (float)a0[j] + c1 * (float)a1[j]) * inv);
  const size_t orow = (size_t)(b * SQ_ + qtA * 128 + row);
  *(bf16x8*)&O[orow * H_ + (size_t)h * HD_ + d8] = o;
}

extern "C" void kernel_launch(void* const* d_in, const int* in_sizes, int n_in,
                              void* d_out, int out_size, void* d_ws, size_t ws_size,
                              hipStream_t stream) {
  const float* hidden = (const float*)d_in[0];
  const float* key    = (const float*)d_in[1];
  const float* value  = (const float*)d_in[2];
  // d_in[3] = attention_mask: pure causal additive mask, applied analytically
  const float* w_q    = (const float*)d_in[4];
  const float* b_q    = (const float*)d_in[5];
  const float* w_proj = (const float*)d_in[6];
  const float* b_proj = (const float*)d_in[7];
  float* out = (float*)d_out;

  const size_t N_HID = (size_t)B_ * SQ_ * H_;
  const size_t N_W   = (size_t)H_ * H_;
  const size_t N_KV  = (size_t)BH_ * SK_ * HD_;
  const float SC2 = 0.08838834764831845f * 1.4426950408889634f;  // 1/sqrt(128)*log2e

  bf16* hid_bf  = (bf16*)d_ws;            // [B*SQ][H]
  bf16* wq_bf   = hid_bf + N_HID;         // [H][H]
  bf16* wp_bf   = wq_bf + N_W;            // [H][H]
  bf16* k_bf    = wp_bf + N_W;            // [BH][SK][HD]
  bf16* vt_bf   = k_bf + N_KV;            // [BH][HD][SK]
  bf16* q_bf    = vt_bf + N_KV;           // [B*SQ][H]
  bf16* part_bf = q_bf + N_HID;           // 512 slots x 128 x 128 bf16 (16.8MB)
  float2* ml_bf = (float2*)(part_bf + (size_t)512 * 128 * 128);  // 64K float2
  bf16* attn_bf = hid_bf;                 // alias: hidden consumed after GEMM1

  cvt3_f32_bf16<<<2048, 256, 0, stream>>>(hidden, hid_bf, w_q, wq_bf, w_proj, wp_bf);
  transpose_cvt2<<<4096, 256, 0, stream>>>(key, value, k_bf, vt_bf);

  // Q = (hidden @ w_q^T + b_q) * SC2  (scale folded into epilogue)
  gemm_bt<bf16><<<(B_ * SQ_ / 128) * (H_ / 128), 256, 0, stream>>>(
      hid_bf, wq_bf, b_q, q_bf, B_ * SQ_, H_, H_, SC2);

  flash_attn<<<512, 256, 0, stream>>>(q_bf, k_bf, vt_bf, attn_bf, part_bf, ml_bf);
  flash_merge<<<2048, 256, 0, stream>>>(part_bf, ml_bf, attn_bf);

  gemm_bt<float><<<(B_ * SQ_ / 128) * (H_ / 128), 256, 0, stream>>>(
      attn_bf, wp_bf, b_proj, out, B_ * SQ_, H_, H_, 1.0f);
}

// Round 12
// 202.916 us; speedup vs baseline: 1.0416x; 1.0416x over previous
//
#include <hip/hip_runtime.h>
#include <hip/hip_bf16.h>

typedef __bf16 bf16;
typedef __bf16 bf16x4 __attribute__((ext_vector_type(4)));
typedef __bf16 bf16x8 __attribute__((ext_vector_type(8)));
typedef float  f32x4  __attribute__((ext_vector_type(4)));
typedef float  f32x16 __attribute__((ext_vector_type(16)));
typedef unsigned int u32;

#define B_   2
#define SQ_  2048
#define SK_  2048
#define H_   2048
#define NH_  16
#define HD_  128
#define BH_  (B_*NH_)

// async 16B global->LDS; LDS dest must be wave-uniform base (+lane*16 by HW)
__device__ inline void gl_lds16(const bf16* g, bf16* l) {
  __builtin_amdgcn_global_load_lds(
      (const __attribute__((address_space(1))) u32*)(const void*)g,
      (__attribute__((address_space(3))) u32*)(void*)l,
      16, 0, 0);
}

__device__ inline float exp2_fast(float x) {
  float r; asm("v_exp_f32 %0, %1" : "=v"(r) : "v"(x)); return r;
}

union PW { u32 w[4]; bf16x8 v; };

// ---- fused pre-pass: fp32->bf16 converts + K/V transpose-converts ---------
// blocks [0,1024): hidden cvt; [1024,1536): w_q; [1536,2048): w_proj;
// [2048,4096): key transpose;  [4096,6144): value transpose.
__global__ __launch_bounds__(256) void prepass(const float* __restrict__ hidden, bf16* __restrict__ hid,
                                               const float* __restrict__ wq, bf16* __restrict__ wqo,
                                               const float* __restrict__ wp, bf16* __restrict__ wpo,
                                               const float* __restrict__ key, const float* __restrict__ value,
                                               bf16* __restrict__ kout, bf16* __restrict__ vout) {
  __shared__ float tile[64][65];
  const int id = blockIdx.x;
  const int t = threadIdx.x;
  if (id < 2048) {
    const float* in; bf16* out; int n4, bstart, nblk;
    if (id < 1024)      { in = hidden; out = hid; n4 = (B_ * SQ_ * H_) / 4; bstart = 0;    nblk = 1024; }
    else if (id < 1536) { in = wq;     out = wqo; n4 = (H_ * H_) / 4;       bstart = 1024; nblk = 512; }
    else                { in = wp;     out = wpo; n4 = (H_ * H_) / 4;       bstart = 1536; nblk = 512; }
    int i = (id - bstart) * 256 + t;
    const int stride = nblk * 256;
    for (; i < n4; i += stride) {
      float4 v = ((const float4*)in)[i];
      bf16x4 w; w[0] = (bf16)v.x; w[1] = (bf16)v.y; w[2] = (bf16)v.z; w[3] = (bf16)v.w;
      ((bf16x4*)out)[i] = w;
    }
    return;
  }
  const int j0 = id - 2048;
  const float* src; bf16* dst; int R, C, r0, c0, bh;
  if (j0 < 2048) {            // key slices: R=HD, C=SK
    src = key; dst = kout; R = HD_; C = SK_;
    c0 = (j0 & 31) * 64; r0 = ((j0 >> 5) & 1) * 64; bh = j0 >> 6;
  } else {                    // value slices: R=SK, C=HD
    const int j = j0 - 2048;
    src = value; dst = vout; R = SK_; C = HD_;
    c0 = (j & 1) * 64; r0 = ((j >> 1) & 31) * 64; bh = j >> 6;
  }
  src += (size_t)bh * R * C;
  dst += (size_t)bh * R * C;
  const int tx = t & 15, ty = t >> 4;
#pragma unroll
  for (int p = 0; p < 4; ++p) {
    int rr = ty + p * 16;
    float4 v = *(const float4*)&src[(size_t)(r0 + rr) * C + c0 + tx * 4];
    tile[rr][tx * 4 + 0] = v.x; tile[rr][tx * 4 + 1] = v.y;
    tile[rr][tx * 4 + 2] = v.z; tile[rr][tx * 4 + 3] = v.w;
  }
  __syncthreads();
#pragma unroll
  for (int p = 0; p < 4; ++p) {
    int cc = ty + p * 16;
    bf16x4 w;
#pragma unroll
    for (int i = 0; i < 4; ++i) w[i] = (bf16)tile[tx * 4 + i][cc];
    *(bf16x4*)&dst[(size_t)(c0 + cc) * R + r0 + tx * 4] = w;
  }
}

// ------- 128x128-tile bf16 GEMM, 3-ring K-tile pipeline, counted vmcnt ------
// C = (A @ Bw^T + bias) * osc.  Ring invariant: at iter t, stage tile t+2 into
// buf[(t+2)%3] (its last readers finished before the iter-(t-1) barrier),
// compute tile t, then vmcnt(4): FIFO retirement => tile t+1's 4 loads done,
// tile t+2's 4 loads stay in flight across the barrier (T4).
// LDS 2-bit XOR swizzle: LDS[row][slot] holds global chunk slot^(row&3);
// reads use g^(row&3) (row&3 == r&3 for frag rows) -> 4-way max conflicts.
template <typename OutT>
__global__ __launch_bounds__(256) void gemm_bt(const bf16* __restrict__ A,
                                               const bf16* __restrict__ Bw,
                                               const float* __restrict__ bias,
                                               OutT* __restrict__ C,
                                               int M, int N, int K, float osc) {
  __shared__ bf16 Abuf[3][128 * 32];
  __shared__ bf16 Bbuf[3][128 * 32];
  const int nbn = N >> 7;
  int wg = blockIdx.x, nwg = gridDim.x;
  int swz = (nwg & 7) ? wg : ((wg & 7) * (nwg >> 3) + (wg >> 3));  // XCD swizzle
  int bm = swz / nbn, bn = swz % nbn;
  const int t = threadIdx.x, lane = t & 63, wid = t >> 6;
  const int r = lane & 15, g = lane >> 4;
  const int wr = wid >> 1, wc = wid & 1;
  const size_t m0 = (size_t)bm * 128, n0 = (size_t)bn * 128;

  // stage source offsets (pre-swizzled): thread covers chunk-units p*256+t
  u32 sOff[2];
#pragma unroll
  for (int p = 0; p < 2; ++p) {
    int c = p * 256 + t, row = c >> 2, off = c & 3, src = off ^ (row & 3);
    sOff[p] = (u32)(row * K + src * 8);
  }
  const bf16* Ab = A + m0 * K;
  const bf16* Bb = Bw + n0 * K;

  f32x4 acc[4][4];
#pragma unroll
  for (int m = 0; m < 4; ++m)
#pragma unroll
    for (int n = 0; n < 4; ++n) acc[m][n] = (f32x4){0.f, 0.f, 0.f, 0.f};

  const int nk = K >> 5;
  // prologue: stage tiles 0,1
#pragma unroll
  for (int kt = 0; kt < 2; ++kt)
#pragma unroll
    for (int p = 0; p < 2; ++p) {
      gl_lds16(Ab + kt * 32 + sOff[p], &Abuf[kt][(p * 256 + wid * 64) * 8]);
      gl_lds16(Bb + kt * 32 + sOff[p], &Bbuf[kt][(p * 256 + wid * 64) * 8]);
    }
  asm volatile("s_waitcnt vmcnt(4)" ::: "memory");  // tile 0 complete
  __syncthreads();

#pragma unroll 1
  for (int kt = 0; kt < nk; ++kt) {
    const int cur = kt % 3;
    if (kt + 2 < nk) {
      const int nb = (kt + 2) % 3;
      const int k0 = (kt + 2) * 32;
#pragma unroll
      for (int p = 0; p < 2; ++p) {
        gl_lds16(Ab + k0 + sOff[p], &Abuf[nb][(p * 256 + wid * 64) * 8]);
        gl_lds16(Bb + k0 + sOff[p], &Bbuf[nb][(p * 256 + wid * 64) * 8]);
      }
    }
    bf16x8 af[4], bfr[4];
#pragma unroll
    for (int m = 0; m < 4; ++m)
      af[m] = *(const bf16x8*)&Abuf[cur][(wr * 64 + m * 16 + r) * 32 + ((g ^ (r & 3)) * 8)];
#pragma unroll
    for (int n = 0; n < 4; ++n)
      bfr[n] = *(const bf16x8*)&Bbuf[cur][(wc * 64 + n * 16 + r) * 32 + ((g ^ (r & 3)) * 8)];
    __builtin_amdgcn_s_setprio(1);
#pragma unroll
    for (int m = 0; m < 4; ++m)
#pragma unroll
      for (int n = 0; n < 4; ++n)
        acc[m][n] = __builtin_amdgcn_mfma_f32_16x16x32_bf16(af[m], bfr[n], acc[m][n], 0, 0, 0);
    __builtin_amdgcn_s_setprio(0);
    if (kt + 2 < nk)
      asm volatile("s_waitcnt vmcnt(4)" ::: "memory");  // tile kt+1 complete
    else
      asm volatile("s_waitcnt vmcnt(0)" ::: "memory");  // drain tail
    __syncthreads();
  }

  float bv[4];
#pragma unroll
  for (int n = 0; n < 4; ++n) bv[n] = bias[n0 + wc * 64 + n * 16 + r];
#pragma unroll
  for (int m = 0; m < 4; ++m)
#pragma unroll
    for (int n = 0; n < 4; ++n)
#pragma unroll
      for (int rr = 0; rr < 4; ++rr) {
        size_t row = m0 + wr * 64 + m * 16 + g * 4 + rr;
        size_t col = n0 + wc * 64 + n * 16 + r;
        C[row * N + col] = (OutT)((acc[m][n][rr] + bv[n]) * osc);
      }
}

// -------- causal flash attention: swapped-operand 32x32, split-kv, T15 ------
// (unchanged from R11 — best measured configuration)
__global__ __launch_bounds__(256, 2) void flash_attn(const bf16* __restrict__ Q,
                                                     const bf16* __restrict__ Kt,
                                                     const bf16* __restrict__ Vt,
                                                     bf16* __restrict__ O,
                                                     bf16* __restrict__ part,
                                                     float2* __restrict__ mlbuf) {
  __shared__ bf16 Klds[2][64 * 128];
  __shared__ bf16 Vlds[3][64 * 128];

  const int id = blockIdx.x;
  const int pr = (id >> 3) & 7;
  const int hf = (id >> 6) & 1;
  const int bh = (id & 7) + 8 * (id >> 7);
  const int qtA = 15 - pr, qtB = pr;
  const int nA = 2 * qtA + 2, nB = 2 * qtB + 2;
  const int b = bh >> 4, h = bh & 15;
  const int t = threadIdx.x, lane = t & 63, wid = t >> 6;
  const int l5 = lane & 31, hiL = lane >> 5;

  const bf16* Kbase = Kt + (size_t)bh * SK_ * HD_;
  const bf16* Vbase = Vt + (size_t)bh * HD_ * SK_;

  u32 kSrc[4], vSrc[4];
#pragma unroll
  for (int p = 0; p < 4; ++p) {
    int c = p * 256 + t;
    { int row = c >> 4, off = c & 15, src = off ^ (row & 15);
      kSrc[p] = (u32)(row * HD_ + src * 8); }
    { int srow = c >> 4, j = c & 15, gj = j ^ (srow & 15);
      int d = srow * 2 + (gj >> 3);
      vSrc[p] = (u32)(d * SK_ + (gj & 7) * 8); }
  }

  const int npass = hf ? 2 : 1;
#pragma unroll 1
  for (int ps = 0; ps < npass; ++ps) {
    int qt, lo, hi, partial;
    if (!hf)          { qt = qtA; lo = 0;  hi = 17; partial = 1; }
    else if (ps == 0) { qt = qtA; lo = 17; hi = nA; partial = 1; }
    else              { qt = qtB; lo = 0;  hi = nB; partial = 0; }
    const int qbw = qt * 128 + wid * 32;
    const int q_lane = qbw + l5;

    bf16x8 qf[8];
    {
      const size_t qrow = (size_t)(b * SQ_ + q_lane) * H_ + (size_t)h * HD_;
#pragma unroll
      for (int dt = 0; dt < 8; ++dt)
        qf[dt] = *(const bf16x8*)&Q[qrow + dt * 16 + 8 * hiL];
    }

    f32x16 acc[4];
#pragma unroll
    for (int n = 0; n < 4; ++n)
#pragma unroll
      for (int e = 0; e < 16; ++e) acc[n][e] = 0.f;
    float mrun = -3.0e38f, lpart = 0.f;

    bf16x8 paP[4];
    bool have_prev = false;
    int kc = 0, vp = 2, vc = 0, vn = 1;

    __syncthreads();
    {
      const size_t ks = (size_t)lo * (64 * HD_), vs = (size_t)lo * 64;
#pragma unroll
      for (int p = 0; p < 4; ++p) {
        gl_lds16(Kbase + ks + kSrc[p], &Klds[0][(p * 256 + wid * 64) * 8]);
        gl_lds16(Vbase + vs + vSrc[p], &Vlds[0][(p * 256 + wid * 64) * 8]);
      }
    }
    asm volatile("s_waitcnt vmcnt(0)" ::: "memory");
    __syncthreads();

#pragma unroll 1
    for (int st = lo; st < hi; ++st) {
      if (st + 1 < hi) {
        const size_t ks = (size_t)(st + 1) * (64 * HD_), vs = (size_t)(st + 1) * 64;
#pragma unroll
        for (int p = 0; p < 4; ++p) {
          gl_lds16(Kbase + ks + kSrc[p], &Klds[kc ^ 1][(p * 256 + wid * 64) * 8]);
          gl_lds16(Vbase + vs + vSrc[p], &Vlds[vn][(p * 256 + wid * 64) * 8]);
        }
      }
      const int s0 = st * 64;
      const bool act = (s0 <= qbw + 31);

      f32x16 sv0, sv1;
      if (act) {
#pragma unroll
        for (int e = 0; e < 16; ++e) { sv0[e] = 0.f; sv1[e] = 0.f; }
        __builtin_amdgcn_s_setprio(1);
#pragma unroll
        for (int dt = 0; dt < 8; ++dt) {
          const int dch = ((2 * dt + hiL) ^ (l5 & 15)) * 8;
          bf16x8 kf0 = *(const bf16x8*)&Klds[kc][l5 * 128 + dch];
          bf16x8 kf1 = *(const bf16x8*)&Klds[kc][(32 + l5) * 128 + dch];
          sv0 = __builtin_amdgcn_mfma_f32_32x32x16_bf16(kf0, qf[dt], sv0, 0, 0, 0);
          sv1 = __builtin_amdgcn_mfma_f32_32x32x16_bf16(kf1, qf[dt], sv1, 0, 0, 0);
        }
        __builtin_amdgcn_s_setprio(0);
      }

      if (have_prev) {
        const bf16* vbuf = &Vlds[vp][0];
        __builtin_amdgcn_s_setprio(1);
#pragma unroll
        for (int n = 0; n < 4; ++n) {
          const int sr = n * 16 + (l5 >> 1);
#pragma unroll
          for (int kt = 0; kt < 4; ++kt) {
            const int jj = ((((l5 & 1) << 3) | (2 * kt + hiL)) ^ (l5 >> 1));
            bf16x8 vf = *(const bf16x8*)&vbuf[sr * 128 + jj * 8];
            acc[n] = __builtin_amdgcn_mfma_f32_32x32x16_bf16(paP[kt], vf, acc[n], 0, 0, 0);
          }
        }
        __builtin_amdgcn_s_setprio(0);
        have_prev = false;
      }

      if (act) {
        if (s0 + 63 > qbw) {
#pragma unroll
          for (int r2 = 0; r2 < 16; ++r2) {
            const int kl = (r2 & 3) + 8 * (r2 >> 2) + 4 * hiL;
            if (s0 + kl > q_lane)      sv0[r2] = -3.0e38f;
            if (s0 + 32 + kl > q_lane) sv1[r2] = -3.0e38f;
          }
        }

        float pm = -3.0e38f;
#pragma unroll
        for (int r2 = 0; r2 < 16; ++r2) pm = fmaxf(pm, fmaxf(sv0[r2], sv1[r2]));
        pm = fmaxf(pm, __shfl_xor(pm, 32));
        if (!__all(pm <= mrun + 10.0f ? 1 : 0)) {
          const float mnew = fmaxf(mrun, pm);
          const float corr = exp2_fast(mrun - mnew);
          mrun = mnew; lpart *= corr;
          const int cb = __float_as_int(corr);
#pragma unroll
          for (int r2 = 0; r2 < 16; ++r2) {
            const int q2 = (r2 & 3) + 8 * (r2 >> 2) + 4 * hiL;
            const float cc = __int_as_float(__builtin_amdgcn_ds_bpermute(q2 * 4, cb));
#pragma unroll
            for (int n = 0; n < 4; ++n) acc[n][r2] *= cc;
          }
        }

        float psum = 0.f;
#pragma unroll
        for (int r2 = 0; r2 < 16; ++r2) {
          sv0[r2] = exp2_fast(sv0[r2] - mrun); psum += sv0[r2];
          sv1[r2] = exp2_fast(sv1[r2] - mrun); psum += sv1[r2];
        }
        lpart += psum;

#pragma unroll
        for (int h2 = 0; h2 < 2; ++h2) {
          u32 pk[8], px[8];
#pragma unroll
          for (int j = 0; j < 8; ++j) {
            union { bf16 hh[2]; u32 u; } tt;
            float plo = h2 ? sv1[2 * j] : sv0[2 * j];
            float phi = h2 ? sv1[2 * j + 1] : sv0[2 * j + 1];
            tt.hh[0] = (bf16)plo; tt.hh[1] = (bf16)phi;
            pk[j] = tt.u;
          }
#pragma unroll
          for (int j = 0; j < 8; ++j) px[j] = (u32)__shfl_xor((int)pk[j], 32);
          PW a0, a1;
          a0.w[0] = hiL ? px[2] : pk[0]; a0.w[1] = hiL ? px[3] : pk[1];
          a0.w[2] = hiL ? pk[2] : px[0]; a0.w[3] = hiL ? pk[3] : px[1];
          a1.w[0] = hiL ? px[6] : pk[4]; a1.w[1] = hiL ? px[7] : pk[5];
          a1.w[2] = hiL ? pk[6] : px[4]; a1.w[3] = hiL ? pk[7] : px[5];
          paP[2 * h2]     = a0.v;
          paP[2 * h2 + 1] = a1.v;
        }
        have_prev = true;
      }

      asm volatile("s_waitcnt vmcnt(0)" ::: "memory");
      __syncthreads();
      kc ^= 1;
      const int ovp = vp; vp = vc; vc = vn; vn = ovp;
    }

    if (have_prev) {
      const bf16* vbuf = &Vlds[vp][0];
#pragma unroll
      for (int n = 0; n < 4; ++n) {
        const int sr = n * 16 + (l5 >> 1);
#pragma unroll
        for (int kt = 0; kt < 4; ++kt) {
          const int jj = ((((l5 & 1) << 3) | (2 * kt + hiL)) ^ (l5 >> 1));
          bf16x8 vf = *(const bf16x8*)&vbuf[sr * 128 + jj * 8];
          acc[n] = __builtin_amdgcn_mfma_f32_32x32x16_bf16(paP[kt], vf, acc[n], 0, 0, 0);
        }
      }
      have_prev = false;
    }

    float ltot = lpart + __shfl_xor(lpart, 32);
    if (partial) {
      const int slot = (hf * 8 + pr) * 32 + bh;
      bf16* pbase = part + (size_t)slot * (128 * 128);
#pragma unroll
      for (int n = 0; n < 4; ++n)
#pragma unroll
        for (int r2 = 0; r2 < 16; ++r2) {
          const int rowt = wid * 32 + (r2 & 3) + 8 * (r2 >> 2) + 4 * hiL;
          pbase[rowt * 128 + n * 32 + l5] = (bf16)acc[n][r2];
        }
      if (lane < 32)
        mlbuf[(size_t)slot * 128 + wid * 32 + lane] = float2{mrun, ltot};
    } else {
      const float inv = 1.0f / ltot;
      const int ib = __float_as_int(inv);
#pragma unroll
      for (int r2 = 0; r2 < 16; ++r2) {
        const int q2 = (r2 & 3) + 8 * (r2 >> 2) + 4 * hiL;
        const float ic = __int_as_float(__builtin_amdgcn_ds_bpermute(q2 * 4, ib));
        const size_t rowg = (size_t)(b * SQ_ + qbw + q2);
#pragma unroll
        for (int n = 0; n < 4; ++n)
          O[rowg * H_ + (size_t)h * HD_ + n * 32 + l5] = (bf16)(acc[n][r2] * ic);
      }
    }
  }
}

// -------- merge the two kv-halves of each qtA tile (vectorized bf16x8) ------
__global__ __launch_bounds__(256) void flash_merge(const bf16* __restrict__ part,
                                                   const float2* __restrict__ mlbuf,
                                                   bf16* __restrict__ O) {
  const int gid = blockIdx.x * 256 + threadIdx.x;   // 524288 threads
  const int idx = gid >> 4;                         // row index in [0, 32768)
  const int d8 = (gid & 15) * 8;
  const int row = idx & 127;
  const int bh = (idx >> 7) & 31;
  const int pr = idx >> 12;
  const int qtA = 15 - pr;
  const int b = bh >> 4, h = bh & 15;
  const int slot0 = pr * 32 + bh;
  const int slot1 = (8 + pr) * 32 + bh;
  const float2 ml0 = mlbuf[(size_t)slot0 * 128 + row];
  const float2 ml1 = mlbuf[(size_t)slot1 * 128 + row];
  const float M = fmaxf(ml0.x, ml1.x);
  const float c0 = exp2_fast(ml0.x - M);
  const float c1 = exp2_fast(ml1.x - M);
  const float inv = 1.0f / (c0 * ml0.y + c1 * ml1.y);
  const bf16x8 a0 = *(const bf16x8*)&part[(size_t)slot0 * (128 * 128) + row * 128 + d8];
  const bf16x8 a1 = *(const bf16x8*)&part[(size_t)slot1 * (128 * 128) + row * 128 + d8];
  bf16x8 o;
#pragma unroll
  for (int j = 0; j < 8; ++j)
    o[j] = (bf16)((c0 * (float)a0[j] + c1 * (float)a1[j]) * inv);
  const size_t orow = (size_t)(b * SQ_ + qtA * 128 + row);
  *(bf16x8*)&O[orow * H_ + (size_t)h * HD_ + d8] = o;
}

extern "C" void kernel_launch(void* const* d_in, const int* in_sizes, int n_in,
                              void* d_out, int out_size, void* d_ws, size_t ws_size,
                              hipStream_t stream) {
  const float* hidden = (const float*)d_in[0];
  const float* key    = (const float*)d_in[1];
  const float* value  = (const float*)d_in[2];
  // d_in[3] = attention_mask: pure causal additive mask, applied analytically
  const float* w_q    = (const float*)d_in[4];
  const float* b_q    = (const float*)d_in[5];
  const float* w_proj = (const float*)d_in[6];
  const float* b_proj = (const float*)d_in[7];
  float* out = (float*)d_out;

  const size_t N_HID = (size_t)B_ * SQ_ * H_;
  const size_t N_W   = (size_t)H_ * H_;
  const size_t N_KV  = (size_t)BH_ * SK_ * HD_;
  const float SC2 = 0.08838834764831845f * 1.4426950408889634f;  // 1/sqrt(128)*log2e

  bf16* hid_bf  = (bf16*)d_ws;            // [B*SQ][H]
  bf16* wq_bf   = hid_bf + N_HID;         // [H][H]
  bf16* wp_bf   = wq_bf + N_W;            // [H][H]
  bf16* k_bf    = wp_bf + N_W;            // [BH][SK][HD]
  bf16* vt_bf   = k_bf + N_KV;            // [BH][HD][SK]
  bf16* q_bf    = vt_bf + N_KV;           // [B*SQ][H]
  bf16* part_bf = q_bf + N_HID;           // 512 slots x 128 x 128 bf16 (16.8MB)
  float2* ml_bf = (float2*)(part_bf + (size_t)512 * 128 * 128);  // 64K float2
  bf16* attn_bf = hid_bf;                 // alias: hidden consumed after GEMM1

  prepass<<<6144, 256, 0, stream>>>(hidden, hid_bf, w_q, wq_bf, w_proj, wp_bf,
                                    key, value, k_bf, vt_bf);

  // Q = (hidden @ w_q^T + b_q) * SC2  (scale folded into epilogue)
  gemm_bt<bf16><<<(B_ * SQ_ / 128) * (H_ / 128), 256, 0, stream>>>(
      hid_bf, wq_bf, b_q, q_bf, B_ * SQ_, H_, H_, SC2);

  flash_attn<<<512, 256, 0, stream>>>(q_bf, k_bf, vt_bf, attn_bf, part_bf, ml_bf);
  flash_merge<<<2048, 256, 0, stream>>>(part_bf, ml_bf, attn_bf);

  gemm_bt<float><<<(B_ * SQ_ / 128) * (H_ / 128), 256, 0, stream>>>(
      attn_bf, wp_bf, b_proj, out, B_ * SQ_, H_, H_, 1.0f);
}